// Round 1
// 196.360 us; speedup vs baseline: 1.1107x; 1.1107x over previous
//
#include <hip/hip_runtime.h>

#define BTOT 1048576
#define D 17
#define H 8
#define OUT 6
#define E 4
#define G1 64
#define G2 32

// Per-expert LDS stride in dwords. 296 % 32 == 8, so expert e's block starts
// at bank 8*e -> the 4 divergent-sel b128 gathers hit disjoint bank groups
// {0..3},{8..11},{16..19},{24..27}: conflict-free. 296*4B = 1184B, 16B-aligned.
#define WSTR 296
// layout within an expert block (dword offsets):
//   [0..135]   eW1  (i*8 + h, 17x8)
//   [136..143] eb1
//   [144..207] eW2  (k*8 + h, 8x8)
//   [208..215] eb2
//   [216..279] eW3  rows padded to 8 (k*8 + o, o<6 valid)
//   [280..285] eb3
//   [286..295] pad

__global__ __launch_bounds__(256) void hybrid_ruc_kernel(
    const float* __restrict__ x,
    const float* __restrict__ eW1, const float* __restrict__ eb1,
    const float* __restrict__ eW2, const float* __restrict__ eb2,
    const float* __restrict__ eW3, const float* __restrict__ eb3,
    const float* __restrict__ gW1, const float* __restrict__ gb1,
    const float* __restrict__ gW2, const float* __restrict__ gb2,
    const float* __restrict__ gW3, const float* __restrict__ gb3,
    float* __restrict__ out)
{
    __shared__ float sx[256 * D];
    __shared__ __align__(16) float swl[E * WSTR];

    const int tid = threadIdx.x;
    const long long bbase = (long long)blockIdx.x * 256;

    // ---- stage this block's x rows into LDS (coalesced) ----
    #pragma unroll
    for (int k = 0; k < D; ++k) {
        int t = tid + k * 256;
        sx[t] = x[bbase * D + t];
    }

    // ---- stage expert weights into LDS (bank-group layout) ----
    for (int t = tid; t < E * D * H; t += 256) {          // eW1: 544
        swl[(t / 136) * WSTR + (t % 136)] = eW1[t];
    }
    {
        int t = tid;
        if (t < E * H * H) {                               // eW2: 256
            swl[(t / 64) * WSTR + 144 + (t % 64)] = eW2[t];
        }
    }
    if (tid < E * H * OUT) {                               // eW3: 192, pad rows to 8
        int e = tid / 48, r = tid % 48, k = r / 6, o = r % 6;
        swl[e * WSTR + 216 + k * 8 + o] = eW3[tid];
    }
    if (tid < E * H) {                                     // eb1: 32
        swl[(tid / 8) * WSTR + 136 + (tid % 8)] = eb1[tid];
    }
    if (tid < E * H) {                                     // eb2: 32
        swl[(tid / 8) * WSTR + 208 + (tid % 8)] = eb2[tid];
    }
    if (tid < E * OUT) {                                   // eb3: 24
        swl[(tid / 6) * WSTR + 280 + (tid % 6)] = eb3[tid];
    }
    __syncthreads();

    // per-thread x row (stride-17 LDS read: 2-way bank alias, free)
    float xr[D];
    #pragma unroll
    for (int i = 0; i < D; ++i) xr[i] = sx[tid * D + i];

    // ---- gating layer1 (17->64) + layer2 (64->32), fused, tiled over j ----
    float h2[G2];
    #pragma unroll
    for (int j = 0; j < G2; ++j) h2[j] = gb2[j];

    #pragma unroll 1
    for (int jt = 0; jt < G1 / 16; ++jt) {      // 4 tiles of 16 hidden units
        float h1t[16];
        #pragma unroll
        for (int c = 0; c < 16; ++c) h1t[c] = gb1[jt * 16 + c];
        #pragma unroll
        for (int i = 0; i < D; ++i) {
            const float xi = xr[i];
            const float* w1row = gW1 + i * G1 + jt * 16;   // uniform addr -> s_load
            #pragma unroll
            for (int c = 0; c < 16; ++c)
                h1t[c] = __builtin_fmaf(xi, w1row[c], h1t[c]);
        }
        #pragma unroll
        for (int c = 0; c < 16; ++c) {
            const float hv = fmaxf(h1t[c], 0.0f);
            const float* w2row = gW2 + (jt * 16 + c) * G2; // uniform addr
            #pragma unroll
            for (int j = 0; j < G2; ++j)
                h2[j] = __builtin_fmaf(hv, w2row[j], h2[j]);
        }
    }

    // ---- gating layer3 (32->4) ----
    float lg[E];
    #pragma unroll
    for (int e = 0; e < E; ++e) lg[e] = gb3[e];
    #pragma unroll
    for (int j = 0; j < G2; ++j) {
        const float hv = fmaxf(h2[j], 0.0f);
        #pragma unroll
        for (int e = 0; e < E; ++e)
            lg[e] = __builtin_fmaf(hv, gW3[j * E + e], lg[e]);
    }

    // ---- argmax, first-max-wins (matches jnp.argmax) ----
    int sel = 0;
    float best = lg[0];
    #pragma unroll
    for (int e = 1; e < E; ++e) {
        if (lg[e] > best) { best = lg[e]; sel = e; }
    }

    // ---- compute ONLY the selected expert; weights gathered from LDS ----
    const float* wl = &swl[sel * WSTR];        // per-lane base, bank-disjoint by e

    float t1[H];
    {
        float4 ba = *(const float4*)(wl + 136);
        float4 bb = *(const float4*)(wl + 140);
        t1[0] = ba.x; t1[1] = ba.y; t1[2] = ba.z; t1[3] = ba.w;
        t1[4] = bb.x; t1[5] = bb.y; t1[6] = bb.z; t1[7] = bb.w;
    }
    #pragma unroll
    for (int i = 0; i < D; ++i) {
        const float xi = xr[i];
        float4 wa = *(const float4*)(wl + i * 8);
        float4 wb = *(const float4*)(wl + i * 8 + 4);
        t1[0] = __builtin_fmaf(xi, wa.x, t1[0]);
        t1[1] = __builtin_fmaf(xi, wa.y, t1[1]);
        t1[2] = __builtin_fmaf(xi, wa.z, t1[2]);
        t1[3] = __builtin_fmaf(xi, wa.w, t1[3]);
        t1[4] = __builtin_fmaf(xi, wb.x, t1[4]);
        t1[5] = __builtin_fmaf(xi, wb.y, t1[5]);
        t1[6] = __builtin_fmaf(xi, wb.z, t1[6]);
        t1[7] = __builtin_fmaf(xi, wb.w, t1[7]);
    }

    float t2[H];
    {
        float4 ba = *(const float4*)(wl + 208);
        float4 bb = *(const float4*)(wl + 212);
        t2[0] = ba.x; t2[1] = ba.y; t2[2] = ba.z; t2[3] = ba.w;
        t2[4] = bb.x; t2[5] = bb.y; t2[6] = bb.z; t2[7] = bb.w;
    }
    #pragma unroll
    for (int k = 0; k < H; ++k) {
        const float tv = fmaxf(t1[k], 0.0f);
        float4 wa = *(const float4*)(wl + 144 + k * 8);
        float4 wb = *(const float4*)(wl + 144 + k * 8 + 4);
        t2[0] = __builtin_fmaf(tv, wa.x, t2[0]);
        t2[1] = __builtin_fmaf(tv, wa.y, t2[1]);
        t2[2] = __builtin_fmaf(tv, wa.z, t2[2]);
        t2[3] = __builtin_fmaf(tv, wa.w, t2[3]);
        t2[4] = __builtin_fmaf(tv, wb.x, t2[4]);
        t2[5] = __builtin_fmaf(tv, wb.y, t2[5]);
        t2[6] = __builtin_fmaf(tv, wb.z, t2[6]);
        t2[7] = __builtin_fmaf(tv, wb.w, t2[7]);
    }

    float pred[OUT];
    {
        float4 ba = *(const float4*)(wl + 280);
        pred[0] = ba.x; pred[1] = ba.y; pred[2] = ba.z; pred[3] = ba.w;
        pred[4] = wl[284]; pred[5] = wl[285];
    }
    #pragma unroll
    for (int k = 0; k < H; ++k) {
        const float tv = fmaxf(t2[k], 0.0f);
        float4 wa = *(const float4*)(wl + 216 + k * 8);     // 6 valid + 2 pad
        float4 wb = *(const float4*)(wl + 216 + k * 8 + 4); // .z/.w are pad, unused
        pred[0] = __builtin_fmaf(tv, wa.x, pred[0]);
        pred[1] = __builtin_fmaf(tv, wa.y, pred[1]);
        pred[2] = __builtin_fmaf(tv, wa.z, pred[2]);
        pred[3] = __builtin_fmaf(tv, wa.w, pred[3]);
        pred[4] = __builtin_fmaf(tv, wb.x, pred[4]);
        pred[5] = __builtin_fmaf(tv, wb.y, pred[5]);
    }

    // ---- store: predictions [B,6] then gating_logits [B,4], flat concat ----
    const long long b = bbase + tid;
    #pragma unroll
    for (int o = 0; o < OUT; ++o) out[b * OUT + o] = pred[o];
    float* lout = out + (long long)BTOT * OUT;
    #pragma unroll
    for (int e = 0; e < E; ++e) lout[b * E + e] = lg[e];
}

extern "C" void kernel_launch(void* const* d_in, const int* in_sizes, int n_in,
                              void* d_out, int out_size, void* d_ws, size_t ws_size,
                              hipStream_t stream) {
    const float* x   = (const float*)d_in[0];
    const float* eW1 = (const float*)d_in[1];
    const float* eb1 = (const float*)d_in[2];
    const float* eW2 = (const float*)d_in[3];
    const float* eb2 = (const float*)d_in[4];
    const float* eW3 = (const float*)d_in[5];
    const float* eb3 = (const float*)d_in[6];
    const float* gW1 = (const float*)d_in[7];
    const float* gb1 = (const float*)d_in[8];
    const float* gW2 = (const float*)d_in[9];
    const float* gb2 = (const float*)d_in[10];
    const float* gW3 = (const float*)d_in[11];
    const float* gb3 = (const float*)d_in[12];
    float* out = (float*)d_out;

    dim3 grid(BTOT / 256), block(256);
    hipLaunchKernelGGL(hybrid_ruc_kernel, grid, block, 0, stream,
                       x, eW1, eb1, eW2, eb2, eW3, eb3,
                       gW1, gb1, gW2, gb2, gW3, gb3, out);
}